// Round 3
// baseline (906.398 us; speedup 1.0000x reference)
//
#include <hip/hip_runtime.h>

#define B_ 2
#define S_ 2048
#define D_ 1024
#define H_ 16
#define HD_ 64

typedef __attribute__((ext_vector_type(8))) short short8;
typedef __attribute__((ext_vector_type(4))) float f32x4;
typedef unsigned short u16;

#define MFMA16(a, b, c) __builtin_amdgcn_mfma_f32_16x16x32_bf16((a), (b), (c), 0, 0, 0)

__device__ __forceinline__ u16 f2bf(float f) {
  union { float f; unsigned u; } v; v.f = f;
  unsigned r = v.u + 0x7FFFu + ((v.u >> 16) & 1u);
  return (u16)(r >> 16);
}
__device__ __forceinline__ float bf2f(u16 h) {
  union { unsigned u; float f; } v; v.u = ((unsigned)h) << 16;
  return v.f;
}

// y = A @ B^T (+bias). A:[4096][1024] f32 row-major. B rows = output features.
// EPI 0: scatter bf16 hi/lo planes into q/k/v [B,H,S,HD]. EPI 1: f32 out [4096][1024].
template <int EPI>
__global__ __launch_bounds__(256, 2) void gemm_split(
    const float* __restrict__ A, const float* __restrict__ B0,
    const float* __restrict__ B1, const float* __restrict__ B2,
    const float* __restrict__ bias0, const float* __restrict__ bias1,
    const float* __restrict__ bias2, u16* __restrict__ oh0, u16* __restrict__ ol0,
    u16* __restrict__ oh1, u16* __restrict__ ol1, u16* __restrict__ oh2,
    u16* __restrict__ ol2, float* __restrict__ outf) {
  __shared__ u16 Ah[128][40], Al[128][40], Bh[128][40], Bl[128][40];
  const int tid = threadIdx.x;
  const int lane = tid & 63, wave = tid >> 6;
  const int wr = wave >> 1, wc = wave & 1;
  const int g = lane >> 4, ln = lane & 15;
  const int mbase = blockIdx.y * 128;
  const int nbase_g = blockIdx.x * 128;
  const int which = nbase_g >> 10;
  const int obase = nbase_g & 1023;
  const float* Bm = (which == 0) ? B0 : (which == 1) ? B1 : B2;
  const float* bias = (which == 0) ? bias0 : (which == 1) ? bias1 : bias2;
  u16* oh = (which == 0) ? oh0 : (which == 1) ? oh1 : oh2;
  u16* ol = (which == 0) ? ol0 : (which == 1) ? ol1 : ol2;

  f32x4 acc[4][4];
  {
    f32x4 z = {0.f, 0.f, 0.f, 0.f};
#pragma unroll
    for (int i = 0; i < 4; ++i)
#pragma unroll
      for (int j = 0; j < 4; ++j) acc[i][j] = z;
  }

  for (int kt = 0; kt < 32; ++kt) {
    const int k0 = kt * 32;
#pragma unroll
    for (int i = 0; i < 4; ++i) {
      const int u = tid + i * 256;
      const int row = u >> 3, col = (u & 7) * 4;
      float4 fa = *(const float4*)&A[(size_t)(mbase + row) * 1024 + k0 + col];
      float4 fb = *(const float4*)&Bm[(size_t)(obase + row) * 1024 + k0 + col];
      float av[4] = {fa.x, fa.y, fa.z, fa.w};
      float bv[4] = {fb.x, fb.y, fb.z, fb.w};
      u16 ah4[4], al4[4], bh4[4], bl4[4];
#pragma unroll
      for (int e = 0; e < 4; ++e) {
        ah4[e] = f2bf(av[e]);
        al4[e] = f2bf(av[e] - bf2f(ah4[e]));
        bh4[e] = f2bf(bv[e]);
        bl4[e] = f2bf(bv[e] - bf2f(bh4[e]));
      }
      *(ushort4*)&Ah[row][col] = make_ushort4(ah4[0], ah4[1], ah4[2], ah4[3]);
      *(ushort4*)&Al[row][col] = make_ushort4(al4[0], al4[1], al4[2], al4[3]);
      *(ushort4*)&Bh[row][col] = make_ushort4(bh4[0], bh4[1], bh4[2], bh4[3]);
      *(ushort4*)&Bl[row][col] = make_ushort4(bl4[0], bl4[1], bl4[2], bl4[3]);
    }
    __syncthreads();
    short8 af[4][2], bfr[4][2];
#pragma unroll
    for (int mi = 0; mi < 4; ++mi) {
      const int r = wr * 64 + mi * 16 + ln;
      af[mi][0] = *(const short8*)&Ah[r][g * 8];
      af[mi][1] = *(const short8*)&Al[r][g * 8];
    }
#pragma unroll
    for (int ni = 0; ni < 4; ++ni) {
      const int r = wc * 64 + ni * 16 + ln;
      bfr[ni][0] = *(const short8*)&Bh[r][g * 8];
      bfr[ni][1] = *(const short8*)&Bl[r][g * 8];
    }
#pragma unroll
    for (int mi = 0; mi < 4; ++mi)
#pragma unroll
      for (int ni = 0; ni < 4; ++ni) {
        acc[mi][ni] = MFMA16(af[mi][0], bfr[ni][0], acc[mi][ni]);
        acc[mi][ni] = MFMA16(af[mi][0], bfr[ni][1], acc[mi][ni]);
        acc[mi][ni] = MFMA16(af[mi][1], bfr[ni][0], acc[mi][ni]);
      }
    __syncthreads();
  }

  // epilogue: C[m][n] at m = (lane>>4)*4+reg, n = lane&15 within each 16x16 frag
  if constexpr (EPI == 0) {
#pragma unroll
    for (int mi = 0; mi < 4; ++mi)
#pragma unroll
      for (int ni = 0; ni < 4; ++ni) {
        const int nl = obase + wc * 64 + ni * 16 + ln;
        const float bv = bias[nl];
        const int hh = nl >> 6, hd = nl & 63;
#pragma unroll
        for (int reg = 0; reg < 4; ++reg) {
          const int mm = mbase + wr * 64 + mi * 16 + g * 4 + reg;
          const int bb = mm >> 11, ss = mm & 2047;
          const size_t dst = ((((size_t)bb * 16 + hh) * 2048) + ss) * 64 + hd;
          const float val = acc[mi][ni][reg] + bv;
          const u16 hi = f2bf(val);
          oh[dst] = hi;
          ol[dst] = f2bf(val - bf2f(hi));
        }
      }
  } else {
#pragma unroll
    for (int mi = 0; mi < 4; ++mi)
#pragma unroll
      for (int ni = 0; ni < 4; ++ni) {
        const int nl = obase + wc * 64 + ni * 16 + ln;
        const float bv = bias[nl];
#pragma unroll
        for (int reg = 0; reg < 4; ++reg) {
          const int mm = mbase + wr * 64 + mi * 16 + g * 4 + reg;
          outf[(size_t)mm * 1024 + nl] = acc[mi][ni][reg] + bv;
        }
      }
  }
}

// Banded attention. Block = 4 waves, 32 q-rows, 576 cols (j0 = i0-256 .. +319).
// Wave w owns cols [w*144, w*144+144) for QK/softmax; d-frag w (16 dims) for PV.
__global__ __launch_bounds__(256, 2) void attn_kernel(
    const u16* __restrict__ qh, const u16* __restrict__ ql,
    const u16* __restrict__ kh, const u16* __restrict__ kl,
    const u16* __restrict__ vh, const u16* __restrict__ vl,
    float* __restrict__ attn, float* __restrict__ ctx) {
  __shared__ u16 Plds[32][584];
  __shared__ u16 Vth[64][136], Vtl[64][136];
  __shared__ float red[2][4][32];

  const int tid = threadIdx.x, lane = tid & 63, wave = tid >> 6;
  const int g = lane >> 4, ln = lane & 15;
  int bid = blockIdx.x;
  bid = (bid & 7) * 256 + (bid >> 3);  // XCD-chunked swizzle (2048 % 8 == 0)
  const int bh = bid >> 6;
  const int qblk = bid & 63;
  const int b = bh >> 4, h = bh & 15;
  const int i0 = qblk * 32;
  const int j0 = i0 - 256;
  const size_t bh_off = (size_t)bh * S_ * HD_;
  const float NINF = -__builtin_inff();

  // Q fragments (hi/lo), A-operand layout: row = ln, k = ks*32 + g*8
  short8 qf[2][2][2];
#pragma unroll
  for (int mi = 0; mi < 2; ++mi)
#pragma unroll
    for (int ks = 0; ks < 2; ++ks) {
      const size_t off = bh_off + (size_t)(i0 + mi * 16 + ln) * 64 + ks * 32 + g * 8;
      qf[mi][ks][0] = *(const short8*)(qh + off);
      qf[mi][ks][1] = *(const short8*)(ql + off);
    }

  // QK^T (split: qh*kh + qh*kl + ql*kh)
  f32x4 acc[2][9];
  {
    f32x4 z = {0.f, 0.f, 0.f, 0.f};
#pragma unroll
    for (int mi = 0; mi < 2; ++mi)
#pragma unroll
      for (int nn = 0; nn < 9; ++nn) acc[mi][nn] = z;
  }
#pragma unroll
  for (int nn = 0; nn < 9; ++nn) {
    const int c = wave * 144 + nn * 16 + ln;
    const int j = j0 + c;
    const int jc = min(max(j, 0), S_ - 1);
    const u16* kp = kh + bh_off + (size_t)jc * 64 + g * 8;
    const u16* lp = kl + bh_off + (size_t)jc * 64 + g * 8;
    short8 bh0 = *(const short8*)kp;
    short8 bh1 = *(const short8*)(kp + 32);
    short8 bl0 = *(const short8*)lp;
    short8 bl1 = *(const short8*)(lp + 32);
#pragma unroll
    for (int mi = 0; mi < 2; ++mi) {
      f32x4 a = acc[mi][nn];
      a = MFMA16(qf[mi][0][0], bh0, a);
      a = MFMA16(qf[mi][1][0], bh1, a);
      a = MFMA16(qf[mi][0][0], bl0, a);
      a = MFMA16(qf[mi][1][0], bl1, a);
      a = MFMA16(qf[mi][0][1], bh0, a);
      a = MFMA16(qf[mi][1][1], bh1, a);
      acc[mi][nn] = a;
    }
  }

  // mask + scale
#pragma unroll
  for (int mi = 0; mi < 2; ++mi)
#pragma unroll
    for (int nn = 0; nn < 9; ++nn) {
      const int c = wave * 144 + nn * 16 + ln;
      const int j = j0 + c;
#pragma unroll
      for (int reg = 0; reg < 4; ++reg) {
        const int r = mi * 16 + g * 4 + reg;
        const bool valid = (j >= 0) && (j < S_) && (c >= r) && (c <= r + 512);
        const float s = acc[mi][nn][reg] * 0.125f;
        acc[mi][nn][reg] = valid ? s : NINF;
      }
    }

  // row max: lane-local over nn, butterfly over 16-lane col group, cross-wave via LDS
  float rmax[2][4];
#pragma unroll
  for (int mi = 0; mi < 2; ++mi)
#pragma unroll
    for (int reg = 0; reg < 4; ++reg) {
      float m = NINF;
#pragma unroll
      for (int nn = 0; nn < 9; ++nn) m = fmaxf(m, acc[mi][nn][reg]);
#pragma unroll
      for (int msk = 1; msk < 16; msk <<= 1) m = fmaxf(m, __shfl_xor(m, msk, 64));
      rmax[mi][reg] = m;
    }
  if (ln == 0) {
#pragma unroll
    for (int mi = 0; mi < 2; ++mi)
#pragma unroll
      for (int reg = 0; reg < 4; ++reg) red[0][wave][mi * 16 + g * 4 + reg] = rmax[mi][reg];
  }
  __syncthreads();
  float gmax[2][4];
#pragma unroll
  for (int mi = 0; mi < 2; ++mi)
#pragma unroll
    for (int reg = 0; reg < 4; ++reg) {
      const int r = mi * 16 + g * 4 + reg;
      gmax[mi][reg] = fmaxf(fmaxf(red[0][0][r], red[0][1][r]), fmaxf(red[0][2][r], red[0][3][r]));
    }

  // exp + partial sums
  float psum[2][4];
#pragma unroll
  for (int mi = 0; mi < 2; ++mi)
#pragma unroll
    for (int reg = 0; reg < 4; ++reg) psum[mi][reg] = 0.f;
#pragma unroll
  for (int mi = 0; mi < 2; ++mi)
#pragma unroll
    for (int nn = 0; nn < 9; ++nn)
#pragma unroll
      for (int reg = 0; reg < 4; ++reg) {
        const float p = __expf(acc[mi][nn][reg] - gmax[mi][reg]);
        acc[mi][nn][reg] = p;
        psum[mi][reg] += p;
      }
#pragma unroll
  for (int mi = 0; mi < 2; ++mi)
#pragma unroll
    for (int reg = 0; reg < 4; ++reg) {
      float s = psum[mi][reg];
#pragma unroll
      for (int msk = 1; msk < 16; msk <<= 1) s += __shfl_xor(s, msk, 64);
      psum[mi][reg] = s;
    }
  if (ln == 0) {
#pragma unroll
    for (int mi = 0; mi < 2; ++mi)
#pragma unroll
      for (int reg = 0; reg < 4; ++reg) red[1][wave][mi * 16 + g * 4 + reg] = psum[mi][reg];
  }
  __syncthreads();
  float inv[2][4];
#pragma unroll
  for (int mi = 0; mi < 2; ++mi)
#pragma unroll
    for (int reg = 0; reg < 4; ++reg) {
      const int r = mi * 16 + g * 4 + reg;
      inv[mi][reg] = 1.f / (red[1][0][r] + red[1][1][r] + red[1][2][r] + red[1][3][r]);
    }

  // band p -> global (fp32) + P -> LDS (bf16)
  float* attn_bh = attn + (size_t)bh * S_ * S_;
#pragma unroll
  for (int mi = 0; mi < 2; ++mi)
#pragma unroll
    for (int nn = 0; nn < 9; ++nn) {
      const int c = wave * 144 + nn * 16 + ln;
      const int j = j0 + c;
#pragma unroll
      for (int reg = 0; reg < 4; ++reg) {
        const int r = mi * 16 + g * 4 + reg;
        const float p = acc[mi][nn][reg] * inv[mi][reg];
        const bool valid = (j >= 0) && (j < S_) && (c >= r) && (c <= r + 512);
        if (valid) attn_bh[(size_t)(i0 + r) * S_ + j] = p;
        Plds[r][c] = f2bf(p);  // p == 0 for invalid cols
      }
    }

  // zero out-of-band region of each row (disjoint from band writes)
  {
    const int r = tid >> 3, tt = tid & 7;
    const int i = i0 + r;
    const int lo = max(0, i - 256), hi = min(S_ - 1, i + 256);
    float* rowp = attn_bh + (size_t)i * S_;
    const float4 z4 = make_float4(0.f, 0.f, 0.f, 0.f);
    const int lo4 = lo >> 2;
    for (int x = tt; x < lo4; x += 8) ((float4*)rowp)[x] = z4;
    if (tt == 0)
      for (int jj = lo & ~3; jj < lo; ++jj) rowp[jj] = 0.f;
    const int t0 = hi + 1;
    int t4 = (t0 + 3) & ~3;
    if (t4 > S_) t4 = S_;
    if (tt == 1)
      for (int jj = t0; jj < t4; ++jj) rowp[jj] = 0.f;
    for (int x = (t4 >> 2) + tt; x < S_ / 4; x += 8) ((float4*)rowp)[x] = z4;
  }
  __syncthreads();  // Plds ready

  // PV: ctx[32][64] = P[32][576] @ V[576][64], V staged transposed in chunks
  f32x4 ctxa[2];
  {
    f32x4 z = {0.f, 0.f, 0.f, 0.f};
    ctxa[0] = z;
    ctxa[1] = z;
  }
  for (int ch = 0; ch < 5; ++ch) {
    const int cw = (ch == 4) ? 64 : 128;
    for (int u = tid; u < cw * 8; u += 256) {
      const int cc = u >> 3, hd0 = (u & 7) * 8;
      const int j = j0 + ch * 128 + cc;
      const int jc = min(max(j, 0), S_ - 1);
      short8 v8 = *(const short8*)(vh + bh_off + (size_t)jc * 64 + hd0);
      short8 w8 = *(const short8*)(vl + bh_off + (size_t)jc * 64 + hd0);
#pragma unroll
      for (int e = 0; e < 8; ++e) {
        Vth[hd0 + e][cc] = (u16)v8[e];
        Vtl[hd0 + e][cc] = (u16)w8[e];
      }
    }
    __syncthreads();
    const int nks = cw >> 5;
    for (int ks = 0; ks < nks; ++ks) {
      const int kc = ks * 32 + g * 8;
      short8 vbh = *(const short8*)&Vth[wave * 16 + ln][kc];
      short8 vbl = *(const short8*)&Vtl[wave * 16 + ln][kc];
#pragma unroll
      for (int mi = 0; mi < 2; ++mi) {
        short8 pa = *(const short8*)&Plds[mi * 16 + ln][ch * 128 + kc];
        ctxa[mi] = MFMA16(pa, vbh, ctxa[mi]);
        ctxa[mi] = MFMA16(pa, vbl, ctxa[mi]);
      }
    }
    __syncthreads();
  }

  // ctx write: [B,S,H*HD] f32
#pragma unroll
  for (int mi = 0; mi < 2; ++mi)
#pragma unroll
    for (int reg = 0; reg < 4; ++reg) {
      const int r = mi * 16 + g * 4 + reg;
      const int d = wave * 16 + ln;
      ctx[(size_t)(b * S_ + i0 + r) * 1024 + h * 64 + d] = ctxa[mi][reg];
    }
}

extern "C" void kernel_launch(void* const* d_in, const int* in_sizes, int n_in,
                              void* d_out, int out_size, void* d_ws, size_t ws_size,
                              hipStream_t stream) {
  (void)in_sizes; (void)n_in; (void)out_size; (void)ws_size;
  const float* x  = (const float*)d_in[0];
  const float* Wq = (const float*)d_in[1];
  const float* bq = (const float*)d_in[2];
  const float* Wk = (const float*)d_in[3];
  const float* bk = (const float*)d_in[4];
  const float* Wv = (const float*)d_in[5];
  const float* bv = (const float*)d_in[6];
  const float* Wo = (const float*)d_in[7];
  const float* bo = (const float*)d_in[8];
  float* out = (float*)d_out;
  float* attn = out + (size_t)B_ * S_ * D_;

  const size_t P = (size_t)B_ * H_ * S_ * HD_;  // 4,194,304 elems
  u16* qh = (u16*)d_ws;
  u16* ql = qh + P;
  u16* kh = ql + P;
  u16* kl = kh + P;
  u16* vh = kl + P;
  u16* vl = vh + P;
  float* ctx = (float*)(vl + P);

  dim3 g1(24, 32);
  gemm_split<0><<<g1, 256, 0, stream>>>(x, Wq, Wk, Wv, bq, bk, bv,
                                        qh, ql, kh, kl, vh, vl, nullptr);
  attn_kernel<<<2048, 256, 0, stream>>>(qh, ql, kh, kl, vh, vl, attn, ctx);
  dim3 g3(8, 32);
  gemm_split<1><<<g3, 256, 0, stream>>>(ctx, Wo, Wo, Wo, bo, bo, bo,
                                        nullptr, nullptr, nullptr, nullptr,
                                        nullptr, nullptr, out);
}

// Round 5
// 802.317 us; speedup vs baseline: 1.1297x; 1.1297x over previous
//
#include <hip/hip_runtime.h>

#define B_ 2
#define S_ 2048
#define D_ 1024
#define H_ 16
#define HD_ 64
#define MSZ 4096  // B_*S_

typedef __attribute__((ext_vector_type(8))) short short8;
typedef __attribute__((ext_vector_type(4))) float f32x4;
typedef unsigned short u16;

#define MFMA16(a, b, c) __builtin_amdgcn_mfma_f32_16x16x32_bf16((a), (b), (c), 0, 0, 0)

typedef __attribute__((address_space(1))) const unsigned int gu32;
typedef __attribute__((address_space(3))) unsigned int lu32;
#define STAGE16(gp, lp) \
  __builtin_amdgcn_global_load_lds((gu32*)(gp), (lu32*)(lp), 16, 0, 0)

__device__ __forceinline__ u16 f2bf(float f) {
  union { float f; unsigned u; } v; v.f = f;
  unsigned r = v.u + 0x7FFFu + ((v.u >> 16) & 1u);
  return (u16)(r >> 16);
}
__device__ __forceinline__ float bf2f(u16 h) {
  union { unsigned u; float f; } v; v.u = ((unsigned)h) << 16;
  return v.f;
}

// Prepass: split fp32 -> bf16 hi/lo planes. Segments in float4 units:
// x: [0,1048576)  Wq,Wk,Wv -> wc concat  Wo: last 262144.
__global__ void split_kernel(const float* __restrict__ x, const float* __restrict__ wq,
                             const float* __restrict__ wk, const float* __restrict__ wv,
                             const float* __restrict__ wo, u16* __restrict__ xh,
                             u16* __restrict__ xl, u16* __restrict__ wch,
                             u16* __restrict__ wcl, u16* __restrict__ woh,
                             u16* __restrict__ wol) {
  const size_t base = (size_t)blockIdx.x * 256 + threadIdx.x;
#pragma unroll
  for (int it = 0; it < 4; ++it) {
    const size_t v = base + (size_t)it * 524288;  // float4 index < 2097152
    float4 f;
    u16 *dh, *dl;
    size_t off;
    if (v < 1048576) {
      f = ((const float4*)x)[v]; dh = xh; dl = xl; off = v;
    } else if (v < 1310720) {
      f = ((const float4*)wq)[v - 1048576]; dh = wch; dl = wcl; off = v - 1048576;
    } else if (v < 1572864) {
      f = ((const float4*)wk)[v - 1310720]; dh = wch; dl = wcl; off = v - 1048576;
    } else if (v < 1835008) {
      f = ((const float4*)wv)[v - 1572864]; dh = wch; dl = wcl; off = v - 1048576;
    } else {
      f = ((const float4*)wo)[v - 1835008]; dh = woh; dl = wol; off = v - 1835008;
    }
    const float e[4] = {f.x, f.y, f.z, f.w};
    u16 h4[4], l4[4];
#pragma unroll
    for (int q = 0; q < 4; ++q) {
      h4[q] = f2bf(e[q]);
      l4[q] = f2bf(e[q] - bf2f(h4[q]));
    }
    *(ushort4*)&dh[off * 4] = make_ushort4(h4[0], h4[1], h4[2], h4[3]);
    *(ushort4*)&dl[off * 4] = make_ushort4(l4[0], l4[1], l4[2], l4[3]);
  }
}

// ctx (4M f32) -> bf16 hi/lo planes.
__global__ void split_ctx(const float* __restrict__ src, u16* __restrict__ dh,
                          u16* __restrict__ dl) {
  const size_t base = (size_t)blockIdx.x * 256 + threadIdx.x;
#pragma unroll
  for (int it = 0; it < 2; ++it) {
    const size_t v = base + (size_t)it * 524288;  // float4 index < 1048576
    float4 f = ((const float4*)src)[v];
    const float e[4] = {f.x, f.y, f.z, f.w};
    u16 h4[4], l4[4];
#pragma unroll
    for (int q = 0; q < 4; ++q) {
      h4[q] = f2bf(e[q]);
      l4[q] = f2bf(e[q] - bf2f(h4[q]));
    }
    *(ushort4*)&dh[v * 4] = make_ushort4(h4[0], h4[1], h4[2], h4[3]);
    *(ushort4*)&dl[v * 4] = make_ushort4(l4[0], l4[1], l4[2], l4[3]);
  }
}

// C = A @ B^T + bias, split-bf16 (3-term Markidis), global_load_lds staging.
template <int EPI>
__global__ __launch_bounds__(256, 2) void gemm_bf(
    const u16* __restrict__ Ahg, const u16* __restrict__ Alg,
    const u16* __restrict__ Bhg, const u16* __restrict__ Blg,
    const float* __restrict__ b0, const float* __restrict__ b1,
    const float* __restrict__ b2, u16* __restrict__ oh, u16* __restrict__ ol,
    float* __restrict__ outf) {
  __shared__ u16 Ah[128 * 32], Al[128 * 32], Bh[128 * 32], Bl[128 * 32];
  const int tid = threadIdx.x, lane = tid & 63, wave = tid >> 6;
  const int wr = wave >> 1, wc = wave & 1;
  const int g = lane >> 4, ln = lane & 15;
  const int mbase = blockIdx.y * 128;
  const int nbase = blockIdx.x * 128;

  f32x4 acc[4][4];
  {
    f32x4 z = {0.f, 0.f, 0.f, 0.f};
#pragma unroll
    for (int i = 0; i < 4; ++i)
#pragma unroll
      for (int j = 0; j < 4; ++j) acc[i][j] = z;
  }

  const int srow = wave * 16 + (lane >> 2);
  const int scol = (lane & 3) * 8;
  const size_t a0 = (size_t)(mbase + srow) * 1024 + scol;
  const size_t a1 = a0 + (size_t)64 * 1024;
  const size_t bo0 = (size_t)(nbase + srow) * 1024 + scol;
  const size_t bo1 = bo0 + (size_t)64 * 1024;
  u16* const lA0 = &Ah[(wave * 16) * 32];
  u16* const lA1 = &Ah[(64 + wave * 16) * 32];
  u16* const lB0 = &Bh[(wave * 16) * 32];
  u16* const lB1 = &Bh[(64 + wave * 16) * 32];
  u16* const lA0l = &Al[(wave * 16) * 32];
  u16* const lA1l = &Al[(64 + wave * 16) * 32];
  u16* const lB0l = &Bl[(wave * 16) * 32];
  u16* const lB1l = &Bl[(64 + wave * 16) * 32];

  for (int kt = 0; kt < 32; ++kt) {
    const int k0 = kt * 32;
    STAGE16(Ahg + a0 + k0, lA0);
    STAGE16(Ahg + a1 + k0, lA1);
    STAGE16(Alg + a0 + k0, lA0l);
    STAGE16(Alg + a1 + k0, lA1l);
    STAGE16(Bhg + bo0 + k0, lB0);
    STAGE16(Bhg + bo1 + k0, lB1);
    STAGE16(Blg + bo0 + k0, lB0l);
    STAGE16(Blg + bo1 + k0, lB1l);
    __syncthreads();
    short8 af[4][2], bf[4][2];
#pragma unroll
    for (int mi = 0; mi < 4; ++mi) {
      const int r = wr * 64 + mi * 16 + ln;
      af[mi][0] = *(const short8*)&Ah[r * 32 + g * 8];
      af[mi][1] = *(const short8*)&Al[r * 32 + g * 8];
    }
#pragma unroll
    for (int ni = 0; ni < 4; ++ni) {
      const int r = wc * 64 + ni * 16 + ln;
      bf[ni][0] = *(const short8*)&Bh[r * 32 + g * 8];
      bf[ni][1] = *(const short8*)&Bl[r * 32 + g * 8];
    }
#pragma unroll
    for (int mi = 0; mi < 4; ++mi)
#pragma unroll
      for (int ni = 0; ni < 4; ++ni) {
        acc[mi][ni] = MFMA16(af[mi][0], bf[ni][0], acc[mi][ni]);
        acc[mi][ni] = MFMA16(af[mi][0], bf[ni][1], acc[mi][ni]);
        acc[mi][ni] = MFMA16(af[mi][1], bf[ni][0], acc[mi][ni]);
      }
    __syncthreads();
  }

  const size_t P = (size_t)B_ * H_ * S_ * HD_;
  if constexpr (EPI == 0) {
#pragma unroll
    for (int mi = 0; mi < 4; ++mi)
#pragma unroll
      for (int ni = 0; ni < 4; ++ni) {
        const int nl3 = nbase + wc * 64 + ni * 16 + ln;  // 0..3071
        const int which = nl3 >> 10;
        const float* bp = (which == 0) ? b0 : (which == 1) ? b1 : b2;
        const float bv = bp[nl3 & 1023];
        const int hh = (nl3 >> 6) & 15, hd = nl3 & 63;
#pragma unroll
        for (int reg = 0; reg < 4; ++reg) {
          const int mm = mbase + wr * 64 + mi * 16 + g * 4 + reg;
          const int bb = mm >> 11, ss = mm & 2047;
          const size_t dst =
              (size_t)which * P + (((size_t)bb * 16 + hh) * 2048 + ss) * 64 + hd;
          const float val = acc[mi][ni][reg] + bv;
          const u16 hi = f2bf(val);
          oh[dst] = hi;
          ol[dst] = f2bf(val - bf2f(hi));
        }
      }
  } else {
#pragma unroll
    for (int mi = 0; mi < 4; ++mi)
#pragma unroll
      for (int ni = 0; ni < 4; ++ni) {
        const int nl = nbase + wc * 64 + ni * 16 + ln;
        const float bv = b0[nl];
#pragma unroll
        for (int reg = 0; reg < 4; ++reg) {
          const int mm = mbase + wr * 64 + mi * 16 + g * 4 + reg;
          outf[(size_t)mm * 1024 + nl] = acc[mi][ni][reg] + bv;
        }
      }
  }
}

// Banded attention. Block = 4 waves, 32 q-rows, 576 cols (j0 = i0-256 .. +319).
__global__ __launch_bounds__(256, 2) void attn_kernel(
    const u16* __restrict__ qh, const u16* __restrict__ ql,
    const u16* __restrict__ kh, const u16* __restrict__ kl,
    const u16* __restrict__ vh, const u16* __restrict__ vl,
    float* __restrict__ attn, float* __restrict__ ctx) {
  __shared__ u16 Plds[32][584];
  __shared__ u16 Vth[64][136], Vtl[64][136];
  __shared__ float red[2][4][32];

  const int tid = threadIdx.x, lane = tid & 63, wave = tid >> 6;
  const int g = lane >> 4, ln = lane & 15;
  int bid = blockIdx.x;
  bid = (bid & 7) * 256 + (bid >> 3);  // XCD-chunked swizzle (2048 % 8 == 0)
  const int bh = bid >> 6;
  const int qblk = bid & 63;
  const int b = bh >> 4, h = bh & 15;
  const int i0 = qblk * 32;
  const int j0 = i0 - 256;
  const size_t bh_off = (size_t)bh * S_ * HD_;
  const float NINF = -__builtin_inff();

  short8 qf[2][2][2];
#pragma unroll
  for (int mi = 0; mi < 2; ++mi)
#pragma unroll
    for (int ks = 0; ks < 2; ++ks) {
      const size_t off = bh_off + (size_t)(i0 + mi * 16 + ln) * 64 + ks * 32 + g * 8;
      qf[mi][ks][0] = *(const short8*)(qh + off);
      qf[mi][ks][1] = *(const short8*)(ql + off);
    }

  f32x4 acc[2][9];
  {
    f32x4 z = {0.f, 0.f, 0.f, 0.f};
#pragma unroll
    for (int mi = 0; mi < 2; ++mi)
#pragma unroll
      for (int nn = 0; nn < 9; ++nn) acc[mi][nn] = z;
  }
#pragma unroll
  for (int nn = 0; nn < 9; ++nn) {
    const int c = wave * 144 + nn * 16 + ln;
    const int j = j0 + c;
    const int jc = min(max(j, 0), S_ - 1);
    const u16* kp = kh + bh_off + (size_t)jc * 64 + g * 8;
    const u16* lp = kl + bh_off + (size_t)jc * 64 + g * 8;
    short8 bh0 = *(const short8*)kp;
    short8 bh1 = *(const short8*)(kp + 32);
    short8 bl0 = *(const short8*)lp;
    short8 bl1 = *(const short8*)(lp + 32);
#pragma unroll
    for (int mi = 0; mi < 2; ++mi) {
      f32x4 a = acc[mi][nn];
      a = MFMA16(qf[mi][0][0], bh0, a);
      a = MFMA16(qf[mi][1][0], bh1, a);
      a = MFMA16(qf[mi][0][0], bl0, a);
      a = MFMA16(qf[mi][1][0], bl1, a);
      a = MFMA16(qf[mi][0][1], bh0, a);
      a = MFMA16(qf[mi][1][1], bh1, a);
      acc[mi][nn] = a;
    }
  }

#pragma unroll
  for (int mi = 0; mi < 2; ++mi)
#pragma unroll
    for (int nn = 0; nn < 9; ++nn) {
      const int c = wave * 144 + nn * 16 + ln;
      const int j = j0 + c;
#pragma unroll
      for (int reg = 0; reg < 4; ++reg) {
        const int r = mi * 16 + g * 4 + reg;
        const bool valid = (j >= 0) && (j < S_) && (c >= r) && (c <= r + 512);
        const float s = acc[mi][nn][reg] * 0.125f;
        acc[mi][nn][reg] = valid ? s : NINF;
      }
    }

  float rmax[2][4];
#pragma unroll
  for (int mi = 0; mi < 2; ++mi)
#pragma unroll
    for (int reg = 0; reg < 4; ++reg) {
      float m = NINF;
#pragma unroll
      for (int nn = 0; nn < 9; ++nn) m = fmaxf(m, acc[mi][nn][reg]);
#pragma unroll
      for (int msk = 1; msk < 16; msk <<= 1) m = fmaxf(m, __shfl_xor(m, msk, 64));
      rmax[mi][reg] = m;
    }
  if (ln == 0) {
#pragma unroll
    for (int mi = 0; mi < 2; ++mi)
#pragma unroll
      for (int reg = 0; reg < 4; ++reg) red[0][wave][mi * 16 + g * 4 + reg] = rmax[mi][reg];
  }
  __syncthreads();
  float gmax[2][4];
#pragma unroll
  for (int mi = 0; mi < 2; ++mi)
#pragma unroll
    for (int reg = 0; reg < 4; ++reg) {
      const int r = mi * 16 + g * 4 + reg;
      gmax[mi][reg] = fmaxf(fmaxf(red[0][0][r], red[0][1][r]), fmaxf(red[0][2][r], red[0][3][r]));
    }

  float psum[2][4];
#pragma unroll
  for (int mi = 0; mi < 2; ++mi)
#pragma unroll
    for (int reg = 0; reg < 4; ++reg) psum[mi][reg] = 0.f;
#pragma unroll
  for (int mi = 0; mi < 2; ++mi)
#pragma unroll
    for (int nn = 0; nn < 9; ++nn)
#pragma unroll
      for (int reg = 0; reg < 4; ++reg) {
        const float p = __expf(acc[mi][nn][reg] - gmax[mi][reg]);
        acc[mi][nn][reg] = p;
        psum[mi][reg] += p;
      }
#pragma unroll
  for (int mi = 0; mi < 2; ++mi)
#pragma unroll
    for (int reg = 0; reg < 4; ++reg) {
      float s = psum[mi][reg];
#pragma unroll
      for (int msk = 1; msk < 16; msk <<= 1) s += __shfl_xor(s, msk, 64);
      psum[mi][reg] = s;
    }
  if (ln == 0) {
#pragma unroll
    for (int mi = 0; mi < 2; ++mi)
#pragma unroll
      for (int reg = 0; reg < 4; ++reg) red[1][wave][mi * 16 + g * 4 + reg] = psum[mi][reg];
  }
  __syncthreads();
  float inv[2][4];
#pragma unroll
  for (int mi = 0; mi < 2; ++mi)
#pragma unroll
    for (int reg = 0; reg < 4; ++reg) {
      const int r = mi * 16 + g * 4 + reg;
      inv[mi][reg] = 1.f / (red[1][0][r] + red[1][1][r] + red[1][2][r] + red[1][3][r]);
    }

  float* attn_bh = attn + (size_t)bh * S_ * S_;
#pragma unroll
  for (int mi = 0; mi < 2; ++mi)
#pragma unroll
    for (int nn = 0; nn < 9; ++nn) {
      const int c = wave * 144 + nn * 16 + ln;
      const int j = j0 + c;
#pragma unroll
      for (int reg = 0; reg < 4; ++reg) {
        const int r = mi * 16 + g * 4 + reg;
        const float p = acc[mi][nn][reg] * inv[mi][reg];
        const bool valid = (j >= 0) && (j < S_) && (c >= r) && (c <= r + 512);
        if (valid) attn_bh[(size_t)(i0 + r) * S_ + j] = p;
        Plds[r][c] = f2bf(p);
      }
    }

  {
    const int r = tid >> 3, tt = tid & 7;
    const int i = i0 + r;
    const int lo = max(0, i - 256), hi = min(S_ - 1, i + 256);
    float* rowp = attn_bh + (size_t)i * S_;
    const float4 z4 = make_float4(0.f, 0.f, 0.f, 0.f);
    const int lo4 = lo >> 2;
    for (int x = tt; x < lo4; x += 8) ((float4*)rowp)[x] = z4;
    if (tt == 0)
      for (int jj = lo & ~3; jj < lo; ++jj) rowp[jj] = 0.f;
    const int t0 = hi + 1;
    int t4 = (t0 + 3) & ~3;
    if (t4 > S_) t4 = S_;
    if (tt == 1)
      for (int jj = t0; jj < t4; ++jj) rowp[jj] = 0.f;
    for (int x = (t4 >> 2) + tt; x < S_ / 4; x += 8) ((float4*)rowp)[x] = z4;
  }
  __syncthreads();

  // PV: V^T staged with XOR swizzle on u16-index bits [4:3] keyed by (row>>3)&3.
  f32x4 ctxa[2];
  {
    f32x4 z = {0.f, 0.f, 0.f, 0.f};
    ctxa[0] = z;
    ctxa[1] = z;
  }
  const int a2 = ((wave * 16 + ln) >> 3) & 3;
  for (int ch = 0; ch < 5; ++ch) {
    const int cw = (ch == 4) ? 64 : 128;
    for (int u = tid; u < cw * 8; u += 256) {
      const int cc = u >> 3, hd0 = (u & 7) * 8;
      const int sw = (u & 3) << 3;
      const int j = j0 + ch * 128 + cc;
      const int jc = min(max(j, 0), S_ - 1);
      short8 v8 = *(const short8*)(vh + bh_off + (size_t)jc * 64 + hd0);
      short8 w8 = *(const short8*)(vl + bh_off + (size_t)jc * 64 + hd0);
      const int cs = cc ^ sw;
#pragma unroll
      for (int e = 0; e < 8; ++e) {
        Vth[hd0 + e][cs] = (u16)v8[e];
        Vtl[hd0 + e][cs] = (u16)w8[e];
      }
    }
    __syncthreads();
    const int nks = cw >> 5;
    for (int ks = 0; ks < nks; ++ks) {
      const int kc = ks * 32 + g * 8;
      const int kcs = kc ^ (a2 << 3);
      short8 vbh = *(const short8*)&Vth[wave * 16 + ln][kcs];
      short8 vbl = *(const short8*)&Vtl[wave * 16 + ln][kcs];
#pragma unroll
      for (int mi = 0; mi < 2; ++mi) {
        short8 pa = *(const short8*)&Plds[mi * 16 + ln][ch * 128 + kc];
        ctxa[mi] = MFMA16(pa, vbh, ctxa[mi]);
        ctxa[mi] = MFMA16(pa, vbl, ctxa[mi]);
      }
    }
    __syncthreads();
  }

#pragma unroll
  for (int mi = 0; mi < 2; ++mi)
#pragma unroll
    for (int reg = 0; reg < 4; ++reg) {
      const int r = mi * 16 + g * 4 + reg;
      const int d = wave * 16 + ln;
      ctx[(size_t)(b * S_ + i0 + r) * 1024 + h * 64 + d] = ctxa[mi][reg];
    }
}

extern "C" void kernel_launch(void* const* d_in, const int* in_sizes, int n_in,
                              void* d_out, int out_size, void* d_ws, size_t ws_size,
                              hipStream_t stream) {
  (void)in_sizes; (void)n_in; (void)out_size; (void)ws_size;
  const float* x  = (const float*)d_in[0];
  const float* Wq = (const float*)d_in[1];
  const float* bq = (const float*)d_in[2];
  const float* Wk = (const float*)d_in[3];
  const float* bk = (const float*)d_in[4];
  const float* Wv = (const float*)d_in[5];
  const float* bv = (const float*)d_in[6];
  const float* Wo = (const float*)d_in[7];
  const float* bo = (const float*)d_in[8];
  float* out = (float*)d_out;
  float* attn = out + (size_t)B_ * S_ * D_;

  const size_t P = (size_t)B_ * H_ * S_ * HD_;  // 4,194,304
  u16* qkvh = (u16*)d_ws;                       // 3P
  u16* qkvl = qkvh + 3 * P;                     // 3P
  float* ctx = (float*)(qkvl + 3 * P);          // 4M f32
  u16* xh = (u16*)(ctx + (size_t)MSZ * 1024);   // 4M
  u16* xl = xh + (size_t)MSZ * 1024;            // 4M
  u16* wch = xl + (size_t)MSZ * 1024;           // 3M
  u16* wcl = wch + 3145728;                     // 3M
  u16* woh = wcl + 3145728;                     // 1M
  u16* wol = woh + 1048576;                     // 1M
  u16* ch  = wol + 1048576;                     // 4M (ctx hi)
  u16* cl  = ch + (size_t)MSZ * 1024;           // 4M (ctx lo)

  split_kernel<<<2048, 256, 0, stream>>>(x, Wq, Wk, Wv, Wo, xh, xl, wch, wcl, woh, wol);

  dim3 g1(24, 32);
  gemm_bf<0><<<g1, 256, 0, stream>>>(xh, xl, wch, wcl, bq, bk, bv,
                                     qkvh, qkvl, nullptr);

  attn_kernel<<<2048, 256, 0, stream>>>(qkvh, qkvl, qkvh + P, qkvl + P,
                                        qkvh + 2 * P, qkvl + 2 * P, attn, ctx);

  split_ctx<<<2048, 256, 0, stream>>>(ctx, ch, cl);

  dim3 g3(8, 32);
  gemm_bf<1><<<g3, 256, 0, stream>>>(ch, cl, woh, wol, bo, bo, bo,
                                     nullptr, nullptr, out);
}